// Round 1
// baseline (86.954 us; speedup 1.0000x reference)
//
#include <hip/hip_runtime.h>
#include <math.h>

#define LSEQ 16384
#define DCH  1000

// ---------------------------------------------------------------------------
// Kernel A: per-channel complex linear recurrence, keep only Re(h[L-1]).
// h_last[d] = sum_{t=0}^{L-1} z_d^{L-1-t} * x_t,   z_d = exp(-exp(size_d)) * e^{i theta_d}
// Parallelized over time with the associative combine:
//   (pa, va) ∘ (pb, vb) = (pa*pb, va*pb + vb)   (a earlier in time than b)
// Each of 256 threads does a 64-step sequential chunk, then wave shfl fold +
// cross-wave LDS fold.
// ---------------------------------------------------------------------------
__global__ __launch_bounds__(256) void scan_last_kernel(
    const float* __restrict__ x, const float* __restrict__ sz,
    const float* __restrict__ th, float* __restrict__ u) {
  const int d = blockIdx.x;
  const int tid = threadIdx.x;

  const float r = expf(-expf(sz[d]));
  const float zr = r * cosf(th[d]);
  const float zi = r * sinf(th[d]);

  // chunk of 64 consecutive timesteps
  const float* xp = x + tid * 64;
  float pr = 1.f, pi = 0.f;   // z^(steps done)
  float vr = 0.f, vi = 0.f;   // running state for this chunk

#pragma unroll
  for (int j4 = 0; j4 < 16; ++j4) {
    float4 xv4 = reinterpret_cast<const float4*>(xp)[j4];
    float xs[4] = {xv4.x, xv4.y, xv4.z, xv4.w};
#pragma unroll
    for (int k = 0; k < 4; ++k) {
      float xv = xs[k];
      float nvr = fmaf(zr, vr, fmaf(-zi, vi, xv));
      float nvi = fmaf(zr, vi, zi * vr);
      vr = nvr; vi = nvi;
      float npr = fmaf(zr, pr, -zi * pi);
      float npi = fmaf(zr, pi, zi * pr);
      pr = npr; pi = npi;
    }
  }

  // wave-level left fold (chunks are in increasing time order by lane)
  const int lane = tid & 63;
  for (int o = 1; o < 64; o <<= 1) {
    float opr = __shfl_down(pr, o);
    float opi = __shfl_down(pi, o);
    float ovr = __shfl_down(vr, o);
    float ovi = __shfl_down(vi, o);
    if (lane + o < 64) {
      float nvr = vr * opr - vi * opi + ovr;
      float nvi = vr * opi + vi * opr + ovi;
      float npr = pr * opr - pi * opi;
      float npi = pr * opi + pi * opr;
      vr = nvr; vi = nvi; pr = npr; pi = npi;
    }
  }

  __shared__ float spr[4], spi[4], svr[4], svi[4];
  const int w = tid >> 6;
  if (lane == 0) { spr[w] = pr; spi[w] = pi; svr[w] = vr; svi[w] = vi; }
  __syncthreads();
  if (tid == 0) {
    float Pr = spr[0], Pi = spi[0], Vr = svr[0], Vi = svi[0];
#pragma unroll
    for (int k = 1; k < 4; ++k) {
      float opr = spr[k], opi = spi[k], ovr = svr[k], ovi = svi[k];
      float nVr = Vr * opr - Vi * opi + ovr;
      float nVi = Vr * opi + Vi * opr + ovi;
      Vr = nVr; Vi = nVi;
      float nPr = Pr * opr - Pi * opi;
      float nPi = Pr * opi + Pi * opr;
      Pr = nPr; Pi = nPi;
    }
    u[d] = Vr;  // only the real part feeds the rest of the network
  }
}

// ---------------------------------------------------------------------------
// Kernel B: x1[j] = relu( sum_d u[d]*W1[j,d] + b1[j] + x[L-1] )
// one block per output row j
// ---------------------------------------------------------------------------
__global__ __launch_bounds__(256) void mv_relu_kernel(
    const float* __restrict__ u, const float* __restrict__ W1,
    const float* __restrict__ b1, const float* __restrict__ x,
    float* __restrict__ x1) {
  const int j = blockIdx.x;
  const int tid = threadIdx.x;
  const float* wrow = W1 + (size_t)j * DCH;
  float acc = 0.f;
  for (int dd = tid; dd < DCH; dd += 256) acc = fmaf(u[dd], wrow[dd], acc);
  for (int o = 32; o > 0; o >>= 1) acc += __shfl_down(acc, o);
  __shared__ float s[4];
  const int lane = tid & 63, w = tid >> 6;
  if (lane == 0) s[w] = acc;
  __syncthreads();
  if (tid == 0) {
    float t = s[0] + s[1] + s[2] + s[3];
    x1[j] = fmaxf(t + b1[j] + x[LSEQ - 1], 0.f);
  }
}

// ---------------------------------------------------------------------------
// Kernel C: logits = x1 @ Wf.T + bf ; softmax ; write 10 floats
// single block
// ---------------------------------------------------------------------------
__global__ __launch_bounds__(256) void head_softmax_kernel(
    const float* __restrict__ x1, const float* __restrict__ Wf,
    const float* __restrict__ bf, float* __restrict__ out) {
  const int tid = threadIdx.x;
  float part[10];
#pragma unroll
  for (int i = 0; i < 10; ++i) part[i] = 0.f;
  for (int dd = tid; dd < DCH; dd += 256) {
    float xv = x1[dd];
#pragma unroll
    for (int i = 0; i < 10; ++i) part[i] = fmaf(xv, Wf[i * DCH + dd], part[i]);
  }
#pragma unroll
  for (int i = 0; i < 10; ++i)
    for (int o = 32; o > 0; o >>= 1) part[i] += __shfl_down(part[i], o);

  __shared__ float s[4][10];
  const int lane = tid & 63, w = tid >> 6;
  if (lane == 0) {
#pragma unroll
    for (int i = 0; i < 10; ++i) s[w][i] = part[i];
  }
  __syncthreads();
  if (tid == 0) {
    float logits[10];
    float m = -1e30f;
#pragma unroll
    for (int i = 0; i < 10; ++i) {
      logits[i] = s[0][i] + s[1][i] + s[2][i] + s[3][i] + bf[i];
      m = fmaxf(m, logits[i]);
    }
    float ssum = 0.f;
#pragma unroll
    for (int i = 0; i < 10; ++i) { logits[i] = expf(logits[i] - m); ssum += logits[i]; }
    float inv = 1.f / ssum;
#pragma unroll
    for (int i = 0; i < 10; ++i) out[i] = logits[i] * inv;
  }
}

extern "C" void kernel_launch(void* const* d_in, const int* in_sizes, int n_in,
                              void* d_out, int out_size, void* d_ws, size_t ws_size,
                              hipStream_t stream) {
  const float* x  = (const float*)d_in[0];  // [16384]
  const float* sz = (const float*)d_in[1];  // [1000]
  const float* th = (const float*)d_in[2];  // [1000]
  const float* W1 = (const float*)d_in[3];  // [1000,1000]
  const float* b1 = (const float*)d_in[4];  // [1000]
  const float* Wf = (const float*)d_in[5];  // [10,1000]
  const float* bf = (const float*)d_in[6];  // [10]
  float* out = (float*)d_out;               // [10]

  float* u  = (float*)d_ws;                 // [1000] Re(h_last)
  float* x1 = u + 1024;                     // [1000] relu'd hidden

  scan_last_kernel<<<DCH, 256, 0, stream>>>(x, sz, th, u);
  mv_relu_kernel<<<DCH, 256, 0, stream>>>(u, W1, b1, x, x1);
  head_softmax_kernel<<<1, 256, 0, stream>>>(x1, Wf, bf, out);
}